// Round 1
// baseline (221.811 us; speedup 1.0000x reference)
//
#include <hip/hip_runtime.h>
#include <hip/hip_bf16.h>

// ---- fused readout: out[1,512] = sum_rows(relu(concat(v0,v1) @ W.T + b)) ----
// M = N_nodes (200000), K = 512 (v0 cols then v1 cols), N_out = 512.
// bf16 MFMA 16x16x32, f32 accumulate. Deterministic 2-stage reduction.

typedef __bf16 bf16x8 __attribute__((ext_vector_type(8)));
typedef float  f32x4  __attribute__((ext_vector_type(4)));

#define BM   128
#define BN   128
#define BK   32
#define NK   16          // 512 / 32
#define LDA  56          // ushort stride per LDS row: 32 data + 24 pad = 112 B (16B-aligned)
#define SLOTS 128        // row-block slots (grid = SLOTS * 4 col-blocks = 512 = 2 blocks/CU)
#define NCB  4           // 512 cols / 128

static __device__ __forceinline__ unsigned short f2bf(float f) {
    __bf16 h = (__bf16)f;                       // RNE; compiler packs pairs into v_cvt_pk_bf16_f32
    return __builtin_bit_cast(unsigned short, h);
}

__global__ __launch_bounds__(256, 2) void fused_gemm_pool(
    const float* __restrict__ v0, const float* __restrict__ v1,
    const float* __restrict__ W,  const float* __restrict__ b,
    float* __restrict__ partial, int N, int numRB)
{
    __shared__ unsigned short As[2][BM * LDA];
    __shared__ unsigned short Bs[2][BN * LDA];
    __shared__ float ldsPart[4][64];

    // XCD-grouped mapping: 4 col-blocks of one slot land on the same XCD (bid%8).
    int bid   = blockIdx.x;
    int group = bid >> 5;          // 32 blocks per group = 8 XCDs x 4 col-blocks
    int xcd   = bid & 7;
    int cb    = (bid >> 3) & 3;    // col-block 0..3
    int slot  = group * 8 + xcd;   // 0..127

    int tid  = threadIdx.x;
    int wid  = tid >> 6;
    int lane = tid & 63;
    int wr   = wid >> 1;           // wave row 0..1 (64 rows each)
    int wc   = wid & 1;            // wave col 0..1 (64 cols each)
    int l15  = lane & 15;
    int l4   = lane >> 4;

    // bias for this lane's 4 n-fragments (col = cb*128 + wc*64 + nf*16 + l15)
    float bv[4];
    #pragma unroll
    for (int nf = 0; nf < 4; ++nf) bv[nf] = b[cb * 128 + wc * 64 + nf * 16 + l15];

    float csum[4] = {0.f, 0.f, 0.f, 0.f};

    float4 ra[4], rbv[4];          // staging registers (A then W)

    for (int rbk = slot; rbk < numRB; rbk += SLOTS) {
        int rowBase = rbk * BM;

        f32x4 acc[4][4];
        #pragma unroll
        for (int mf = 0; mf < 4; ++mf)
            #pragma unroll
            for (int nf = 0; nf < 4; ++nf)
                acc[mf][nf] = (f32x4){0.f, 0.f, 0.f, 0.f};

        // ---- staging helpers ----
        auto loadRegs = [&](int kt) {
            int k0 = kt * BK;
            const float* srcA = (k0 < 256) ? (v0 + (size_t)rowBase * 256 + k0)
                                           : (v1 + (size_t)rowBase * 256 + (k0 - 256));
            #pragma unroll
            for (int i = 0; i < 4; ++i) {
                int idx = tid + i * 256;           // 0..1023 float4 slots (128 rows x 8)
                int row = idx >> 3, kq = idx & 7;
                float4 f = {0.f, 0.f, 0.f, 0.f};
                if (rowBase + row < N)
                    f = *(const float4*)(srcA + (size_t)row * 256 + kq * 4);
                ra[i] = f;
                rbv[i] = *(const float4*)(W + (size_t)(cb * 128 + row) * 512 + k0 + kq * 4);
            }
        };
        auto writeLds = [&](int buf) {
            #pragma unroll
            for (int i = 0; i < 4; ++i) {
                int idx = tid + i * 256;
                int row = idx >> 3, kq = idx & 7;
                union { unsigned short u[4]; uint2 v; } pa, pb;
                pa.u[0] = f2bf(ra[i].x);  pa.u[1] = f2bf(ra[i].y);
                pa.u[2] = f2bf(ra[i].z);  pa.u[3] = f2bf(ra[i].w);
                pb.u[0] = f2bf(rbv[i].x); pb.u[1] = f2bf(rbv[i].y);
                pb.u[2] = f2bf(rbv[i].z); pb.u[3] = f2bf(rbv[i].w);
                *(uint2*)&As[buf][row * LDA + kq * 4] = pa.v;
                *(uint2*)&Bs[buf][row * LDA + kq * 4] = pb.v;
            }
        };
        auto compute = [&](int buf) {
            bf16x8 af[4], bfr[4];
            #pragma unroll
            for (int mf = 0; mf < 4; ++mf) {
                int r = wr * 64 + mf * 16 + l15;
                af[mf] = *(const bf16x8*)&As[buf][r * LDA + l4 * 8];
            }
            #pragma unroll
            for (int nf = 0; nf < 4; ++nf) {
                int c = wc * 64 + nf * 16 + l15;
                bfr[nf] = *(const bf16x8*)&Bs[buf][c * LDA + l4 * 8];
            }
            #pragma unroll
            for (int mf = 0; mf < 4; ++mf)
                #pragma unroll
                for (int nf = 0; nf < 4; ++nf)
                    acc[mf][nf] = __builtin_amdgcn_mfma_f32_16x16x32_bf16(
                        af[mf], bfr[nf], acc[mf][nf], 0, 0, 0);
        };

        // ---- K loop: double-buffered, loads issued before the barrier ----
        loadRegs(0);
        __syncthreads();           // protect buffers from previous row-block's compute
        writeLds(0);
        int cur = 0;
        for (int kt = 0; kt < NK; ++kt) {
            if (kt + 1 < NK) loadRegs(kt + 1);   // VMEM in flight across barrier
            __syncthreads();                     // buf[cur] fully staged
            compute(cur);
            if (kt + 1 < NK) writeLds(cur ^ 1);
            cur ^= 1;
        }

        // ---- epilogue: bias + relu + row-mask -> per-lane column partials ----
        #pragma unroll
        for (int nf = 0; nf < 4; ++nf) {
            float bb = bv[nf];
            #pragma unroll
            for (int mf = 0; mf < 4; ++mf) {
                int rbase = rowBase + wr * 64 + mf * 16 + l4 * 4;
                #pragma unroll
                for (int r = 0; r < 4; ++r) {
                    float v = acc[mf][nf][r] + bb;
                    v = fmaxf(v, 0.f);
                    if (rbase + r < N) csum[nf] += v;
                }
            }
        }
    }

    // ---- cross-lane column reduce: lanes l, l^16, l^32, l^48 share a column ----
    #pragma unroll
    for (int nf = 0; nf < 4; ++nf) {
        float s = csum[nf];
        s += __shfl_xor(s, 16);
        s += __shfl_xor(s, 32);
        if (lane < 16) ldsPart[wid][nf * 16 + lane] = s;
    }
    __syncthreads();
    if (tid < 128) {
        int half = tid >> 6, c = tid & 63;
        float v = ldsPart[half][c] + ldsPart[half + 2][c];
        partial[(size_t)slot * 512 + cb * 128 + tid] = v;
    }
}

__global__ void reduce_partials(const float* __restrict__ partial, float* __restrict__ out)
{
    int c = blockIdx.x * blockDim.x + threadIdx.x;
    if (c < 512) {
        float s = 0.f;
        for (int s2 = 0; s2 < SLOTS; ++s2) s += partial[(size_t)s2 * 512 + c];
        out[c] = s;
    }
}

extern "C" void kernel_launch(void* const* d_in, const int* in_sizes, int n_in,
                              void* d_out, int out_size, void* d_ws, size_t ws_size,
                              hipStream_t stream)
{
    const float* v0 = (const float*)d_in[0];
    const float* v1 = (const float*)d_in[1];
    const float* W  = (const float*)d_in[2];
    const float* b  = (const float*)d_in[3];
    float* out      = (float*)d_out;
    float* partial  = (float*)d_ws;            // SLOTS*512 floats = 256 KB

    int N = in_sizes[0] / 256;
    int numRB = (N + BM - 1) / BM;

    fused_gemm_pool<<<dim3(SLOTS * NCB), dim3(256), 0, stream>>>(
        v0, v1, W, b, partial, N, numRB);
    reduce_partials<<<dim3(2), dim3(256), 0, stream>>>(partial, out);
}